// Round 1
// baseline (1027.788 us; speedup 1.0000x reference)
//
#include <hip/hip_runtime.h>

#define NN   8192
#define DD   128
#define KK   8
#define KM1  7
#define ROWS 4
#define TPB  256

#define O0_END   57344
#define O1_END   7397376
#define O2_END   14737408
#define O3_END   22077440
#define TOTAL    23126016

__device__ __forceinline__ unsigned mix32(unsigned h) {
  h ^= h >> 16; h *= 0x85ebca6bu; h ^= h >> 13; h *= 0xc2b2ae35u; h ^= h >> 16;
  return h;
}

// One block handles ROWS consecutive anchor rows. For each row i it draws
// KM1 independent categorical samples over columns j with
//   logit(j) = -63*ln(d2m) - 62.5*ln(om)   (masked: same k-block or dist>=1.4)
// via Gumbel-argmax with a deterministic counter-based hash RNG.
__global__ __launch_bounds__(TPB) void sample_negatives(const float* __restrict__ x,
                                                        int* __restrict__ nidx) {
  __shared__ float xa[ROWS][DD];
  __shared__ float red_s[ROWS][KM1][TPB / 64];
  __shared__ int   red_i[ROWS][KM1][TPB / 64];

  const int tid = threadIdx.x;
  const int i0  = blockIdx.x * ROWS;

  for (int t = tid; t < ROWS * DD; t += TPB) {
    xa[t / DD][t % DD] = x[i0 * DD + t];
  }
  __syncthreads();

  float best[ROWS][KM1];
  int   bidx[ROWS][KM1];
#pragma unroll
  for (int r = 0; r < ROWS; ++r)
#pragma unroll
    for (int s = 0; s < KM1; ++s) { best[r][s] = -1e30f; bidx[r][s] = 0; }

  for (int col = tid; col < NN; col += TPB) {
    const float4* xj = reinterpret_cast<const float4*>(x + (size_t)col * DD);
    float dot[ROWS] = {0.f, 0.f, 0.f, 0.f};
#pragma unroll 8
    for (int d4 = 0; d4 < DD / 4; ++d4) {
      float4 v = xj[d4];
#pragma unroll
      for (int r = 0; r < ROWS; ++r) {
        float4 a = reinterpret_cast<const float4*>(xa[r])[d4];  // LDS broadcast
        dot[r] += v.x * a.x + v.y * a.y + v.z * a.z + v.w * a.w;
      }
    }
#pragma unroll
    for (int r = 0; r < ROWS; ++r) {
      const int i = i0 + r;
      float d2m = fmaxf(2.0f - 2.0f * dot[r], 0.25f);          // clamped dist^2
      bool valid = ((col >> 3) != (i >> 3)) && (d2m < 1.96f);  // block mask + dist<1.4
      if (valid) {
        float om   = fmaxf(1.0f - 0.25f * d2m, 1e-8f);
        float logw = -63.0f * __logf(d2m) - 62.5f * __logf(om);
        unsigned h = mix32((unsigned)(i * NN + col) + 0x9E3779B9u);
#pragma unroll
        for (int sm = 0; sm < KM1; ++sm) {
          h = h * 1664525u + 1013904223u;
          float u = ((float)(h >> 9) + 0.5f) * (1.0f / 8388608.0f);  // (0,1)
          float g = -__logf(-__logf(u));                             // Gumbel
          float sc = logw + g;
          if (sc > best[r][sm]) { best[r][sm] = sc; bidx[r][sm] = col; }
        }
      }
    }
  }

  const int lane = tid & 63;
  const int wv   = tid >> 6;
#pragma unroll
  for (int r = 0; r < ROWS; ++r) {
#pragma unroll
    for (int sm = 0; sm < KM1; ++sm) {
      float sc = best[r][sm];
      int   ix = bidx[r][sm];
#pragma unroll
      for (int off = 32; off > 0; off >>= 1) {
        float os = __shfl_down(sc, off);
        int   oi = __shfl_down(ix, off);
        if (os > sc) { sc = os; ix = oi; }
      }
      if (lane == 0) { red_s[r][sm][wv] = sc; red_i[r][sm][wv] = ix; }
    }
  }
  __syncthreads();

  if (tid < ROWS * KM1) {
    int r = tid / KM1, sm = tid % KM1;
    float sc = red_s[r][sm][0];
    int   ix = red_i[r][sm][0];
    for (int w = 1; w < TPB / 64; ++w) {
      if (red_s[r][sm][w] > sc) { sc = red_s[r][sm][w]; ix = red_i[r][sm][w]; }
    }
    const int i = i0 + r;
    if (sc < -1e29f) {  // degenerate row -> uniform fallback (mirrors probs = 1/n)
      ix = (int)(mix32((unsigned)(i * KM1 + sm) * 0x68bc21ebu + 77u) & (NN - 1));
    }
    nidx[i * KM1 + sm] = ix;
  }
}

// Writes all five output chunks, concatenated flat (float32).
__global__ __launch_bounds__(256) void write_outputs(const float* __restrict__ x,
                                                     const int* __restrict__ nidx,
                                                     float* __restrict__ out) {
  int e = blockIdx.x * 256 + threadIdx.x;
  if (e >= TOTAL) return;
  float v;
  if (e < O0_END) {
    v = (float)(e / KM1);                                  // a_idx
  } else if (e < O1_END) {
    int t = e - O0_END; int sidx = t >> 7; int d = t & 127;
    v = x[(sidx / KM1) * DD + d];                          // x[a_idx]
  } else if (e < O2_END) {
    int t = e - O1_END; int sidx = t >> 7; int d = t & 127;
    int i = sidx / KM1; int j = sidx - i * KM1; int m = i & (KK - 1);
    int p = (i >> 3) * KK + j + (j >= m ? 1 : 0);          // block members, skip self
    v = x[p * DD + d];                                     // x[p_idx]
  } else if (e < O3_END) {
    int t = e - O2_END; int sidx = t >> 7; int d = t & 127;
    v = x[nidx[sidx] * DD + d];                            // x[n_idx]
  } else {
    v = x[e - O3_END];                                     // x passthrough
  }
  out[e] = v;
}

extern "C" void kernel_launch(void* const* d_in, const int* in_sizes, int n_in,
                              void* d_out, int out_size, void* d_ws, size_t ws_size,
                              hipStream_t stream) {
  const float* x = (const float*)d_in[0];
  float* out = (float*)d_out;
  int* nidx = (int*)d_ws;  // 57344 ints of scratch

  hipLaunchKernelGGL(sample_negatives, dim3(NN / ROWS), dim3(TPB), 0, stream, x, nidx);
  hipLaunchKernelGGL(write_outputs, dim3((TOTAL + 255) / 256), dim3(256), 0, stream,
                     x, nidx, out);
}